// Round 6
// baseline (108.535 us; speedup 1.0000x reference)
//
#include <hip/hip_runtime.h>

// Problem constants (from reference)
constexpr int B = 16384;
constexpr int T = 256;
constexpr int D = 8;
constexpr int F = 512;
constexpr int C = 16;
constexpr int L = 256;  // 2^D

typedef float f32x4 __attribute__((ext_vector_type(4)));

struct FP { int fidx; float thr; };  // packed per-(t,d) node info, 8 B

// Kernel 1: per (t,d) argmax over F=512 feature weights, first-occurrence
// tie-break to match jnp.argmax. One wave per row; 4 rows per 256-thread block.
__global__ __launch_bounds__(256) void node_prep_kernel(
    const float* __restrict__ fw,      // (T, D, F)
    const float* __restrict__ thr,     // (T, D)
    FP* __restrict__ packed)           // (T*D)
{
    const int wave = threadIdx.x >> 6;
    const int lane = threadIdx.x & 63;
    const int row  = blockIdx.x * 4 + wave;          // [0, T*D)
    const float* base = fw + (size_t)row * F;

    float best = -INFINITY;
    int bidx = 0;
#pragma unroll
    for (int k = 0; k < F / 64; ++k) {
        const int idx = lane + k * 64;
        const float v = base[idx];
        if (v > best) { best = v; bidx = idx; }
    }
#pragma unroll
    for (int off = 32; off >= 1; off >>= 1) {
        const float ov = __shfl_xor(best, off);
        const int   oi = __shfl_xor(bidx, off);
        if (ov > best || (ov == best && oi < bidx)) { best = ov; bidx = oi; }
    }
    if (lane == 0) {
        FP p;
        p.fidx = bidx;
        p.thr  = thr[row];
        packed[row] = p;
    }
}

// Kernel 2a: decisions only. 4 samples per block; stage x rows in LDS;
// thread t computes tree t's decision byte for 4 samples; pack via LDS and
// write 1 KB per block coalesced. dec layout: dec[b][t] bytes, row = 256 B.
__global__ __launch_bounds__(256) void decide_kernel(
    const float* __restrict__ x,          // (B, F)
    const FP* __restrict__ packed,        // (T*D)
    unsigned int* __restrict__ dec)       // (B * 64) words
{
    __shared__ float xrow[4][F];             // 8 KB
    __shared__ unsigned char sdec[4][T];     // 1 KB

    const int b0  = blockIdx.x * 4;
    const int tid = threadIdx.x;

    {
        const float4* xs = reinterpret_cast<const float4*>(x + (size_t)b0 * F);
        float4* xl = reinterpret_cast<float4*>(&xrow[0][0]);
        xl[tid]       = xs[tid];
        xl[tid + 256] = xs[tid + 256];
    }
    __syncthreads();

    {
        const int2* p2 = reinterpret_cast<const int2*>(packed) + tid * D;
        int2 raw[D];
#pragma unroll
        for (int d = 0; d < D; ++d) raw[d] = p2[d];
        int dec0 = 0, dec1 = 0, dec2 = 0, dec3 = 0;
#pragma unroll
        for (int d = 0; d < D; ++d) {
            const int   f  = raw[d].x;
            const float th = __int_as_float(raw[d].y);
            const int   p  = 128 >> d;            // powers = 2^(D-1-d)
            dec0 |= (xrow[0][f] > th) ? p : 0;
            dec1 |= (xrow[1][f] > th) ? p : 0;
            dec2 |= (xrow[2][f] > th) ? p : 0;
            dec3 |= (xrow[3][f] > th) ? p : 0;
        }
        sdec[0][tid] = (unsigned char)dec0;
        sdec[1][tid] = (unsigned char)dec1;
        sdec[2][tid] = (unsigned char)dec2;
        sdec[3][tid] = (unsigned char)dec3;
    }
    __syncthreads();

    // coalesced 1 KB write: 256 threads x 1 word
    dec[blockIdx.x * 256 + tid] = reinterpret_cast<const unsigned int*>(&sdec[0][0])[tid];
}

// Kernel 2b: gathers only. One wave per sample; no LDS, no barriers.
// lane: tree-in-group = lane>>2 (0..15), channel quad = lane&3.
// 4 consecutive lanes cover one 64 B leaf row. Decision words arrive via one
// coalesced 256 B row load + __shfl broadcast. 16 independent float4 gathers
// held in a named register array so all are in flight simultaneously.
__global__ __launch_bounds__(256, 4) void gather_kernel(
    const unsigned int* __restrict__ dec, // (B * 64) words
    const float* __restrict__ responses,  // (T, L, C)
    float* __restrict__ out)              // (B, C)
{
    const int tid  = threadIdx.x;
    const int w    = tid >> 6;
    const int lane = tid & 63;
    const int s    = blockIdx.x * 4 + w;   // sample

    // one coalesced 256 B decision-row read: lane holds word `lane`
    const unsigned int w0 = dec[s * 64 + lane];

    const int wsel = lane >> 4;
    const int bsel = ((lane >> 2) & 3) * 8;       // byte within word = t&3
    // per-lane constant offset: tree-in-group<<12 | channel<<2
    const int lbase = ((lane >> 2) << 12) | ((lane & 3) << 2);

    int dw[16];
#pragma unroll
    for (int kk = 0; kk < 16; ++kk) dw[kk] = __shfl((int)w0, 4 * kk + wsel);

    float4 r[16];
#pragma unroll
    for (int kk = 0; kk < 16; ++kk) {
        const int dd = (dw[kk] >> bsel) & 255;
        r[kk] = *reinterpret_cast<const float4*>(
            responses + (kk << 16) + (dd << 4) + lbase);
    }

    float4 acc = r[0];
#pragma unroll
    for (int kk = 1; kk < 16; ++kk) {
        acc.x += r[kk].x; acc.y += r[kk].y;
        acc.z += r[kk].z; acc.w += r[kk].w;
    }

    // reduce across tree-in-group bits (lane bits 2..5)
#pragma unroll
    for (int off = 4; off <= 32; off <<= 1) {
        acc.x += __shfl_xor(acc.x, off);
        acc.y += __shfl_xor(acc.y, off);
        acc.z += __shfl_xor(acc.z, off);
        acc.w += __shfl_xor(acc.w, off);
    }

    if (lane < 4) {
        const float sc = 1.0f / T;
        f32x4 o = { acc.x * sc, acc.y * sc, acc.z * sc, acc.w * sc };
        *reinterpret_cast<f32x4*>(out + ((size_t)s << 4) + (lane << 2)) = o;
    }
}

extern "C" void kernel_launch(void* const* d_in, const int* in_sizes, int n_in,
                              void* d_out, int out_size, void* d_ws, size_t ws_size,
                              hipStream_t stream) {
    const float* x         = (const float*)d_in[0];  // (B, F)
    const float* fw        = (const float*)d_in[1];  // (T, D, F)
    const float* thr       = (const float*)d_in[2];  // (T, D)
    const float* responses = (const float*)d_in[3];  // (T, L, C)
    float* out             = (float*)d_out;          // (B, C)

    FP* packed        = (FP*)d_ws;                               // 16 KB
    unsigned int* dec = (unsigned int*)((char*)d_ws + 65536);    // 4 MB

    node_prep_kernel<<<(T * D) / 4, 256, 0, stream>>>(fw, thr, packed);
    decide_kernel<<<B / 4, 256, 0, stream>>>(x, packed, dec);
    gather_kernel<<<B / 4, 256, 0, stream>>>(dec, responses, out);
}